// Round 5
// baseline (136.594 us; speedup 1.0000x reference)
//
#include <hip/hip_runtime.h>
#include <hip/hip_bf16.h>
#include <cstdint>
#include <cstddef>

// Problem constants (fixed by the reference: anchor/positive [4096,512] f32, labels [4096] i32)
constexpr int BN = 4096;   // batch
constexpr int DN = 512;    // feature dim
constexpr int NT = BN / 128;              // 32 tiles per dim
constexpr int NBLK = NT * (NT + 1) / 2;   // 528 triangular tile-pairs
constexpr float MARGIN = 0.2f;
constexpr uint32_t INF_U = 0x7f800000u;   // +inf bits; positive-float order == uint order

typedef __attribute__((ext_vector_type(8))) short short8;     // 8 bf16 = 4 VGPRs (MFMA A/B frag)
typedef __attribute__((ext_vector_type(4))) float float4v;    // MFMA C/D frag

// ---------------------------------------------------------------------------
// Kernel 1: per-row stats + bf16 cast of anchor + init of min arrays + counter.
// One wave per row (4 rows / 256-thread block). Lane l owns elems [8l, 8l+8).
// meta[row] = {||a||^2, d_ap(squared), d_ap^2, label-bits}  (one b128 load later)
// ---------------------------------------------------------------------------
__global__ __launch_bounds__(256) void prep_kernel(
    const float* __restrict__ anchor,
    const float* __restrict__ positive,
    const int* __restrict__ labels,
    uint16_t* __restrict__ Abf,        // [BN][DN] bf16 bits
    float4* __restrict__ meta,         // [BN]
    uint32_t* __restrict__ min_all,    // [BN] +inf-initialized (min over d2)
    uint32_t* __restrict__ min_larger, // [BN] +inf-initialized (min over d2)
    uint32_t* __restrict__ done_count) // single counter, zeroed here
{
    const int tid  = threadIdx.x;
    const int wave = tid >> 6;
    const int lane = tid & 63;
    const int row  = blockIdx.x * 4 + wave;

    if (blockIdx.x == 0 && tid == 0) *done_count = 0;

    const float4* arow = (const float4*)(anchor   + (size_t)row * DN);
    const float4* prow = (const float4*)(positive + (size_t)row * DN);

    float4 av0 = arow[lane * 2 + 0], av1 = arow[lane * 2 + 1];
    float4 pv0 = prow[lane * 2 + 0], pv1 = prow[lane * 2 + 1];

    float a[8] = {av0.x, av0.y, av0.z, av0.w, av1.x, av1.y, av1.z, av1.w};
    float p[8] = {pv0.x, pv0.y, pv0.z, pv0.w, pv1.x, pv1.y, pv1.z, pv1.w};

    float s = 0.f, d = 0.f;
    union { uint16_t u[8]; uint4 v; } pk;
    #pragma unroll
    for (int i = 0; i < 8; ++i) {
        s += a[i] * a[i];
        float dx = a[i] - p[i];
        d += dx * dx;
        uint32_t ub = __float_as_uint(a[i]);               // RNE f32 -> bf16
        pk.u[i] = (uint16_t)((ub + 0x7fffu + ((ub >> 16) & 1u)) >> 16);
    }

    ((uint4*)(Abf + (size_t)row * DN))[lane] = pk.v;       // 16B coalesced store

    #pragma unroll
    for (int off = 32; off; off >>= 1) {
        s += __shfl_xor(s, off);
        d += __shfl_xor(d, off);
    }
    if (lane == 0) {
        meta[row] = (float4){s, d, d * d, __uint_as_float((uint32_t)labels[row])};
        min_all[row]    = INF_U;
        min_larger[row] = INF_U;
    }
}

// ---------------------------------------------------------------------------
// Kernel 2: upper-triangular 128x128 tiles of S = A·A^T (bf16 MFMA 16x16x32).
// NO LDS STAGING, NO K-LOOP BARRIERS: the MFMA A/B fragment layout is 16 B
// contiguous per lane (A[m=lane&15][k=quad*8+j] -> addr row*DN + quad*8), so
// fragments load straight from global as b128. Each wave is an independent
// 128-load / 256-MFMA stream, even/odd double-buffered (compile-time indices,
// no register copies). Abf (4 MB) fits per-XCD L2 -> loads are L2 hits hidden
// by 12 waves/CU of ILP. [R1/R3: global_load_lds chain serialized ~2.2k cyc/
// instr = 58 µs wall; R4 LDS-staged 2-barrier loop = 41 µs, all pipes <15%
// busy -> sync-bound; this removes the syncs.]
// Epilogue: squared-distance dual-side masked mins via uint atomicMin.
// Last block (device counter) folds in the finalize: select, sqrt, hinge, mean.
// ---------------------------------------------------------------------------
__global__ __launch_bounds__(256, 3) void gram_kernel(
    const uint16_t* __restrict__ Abf,
    const float4* __restrict__ meta,
    uint32_t* __restrict__ min_all,
    uint32_t* __restrict__ min_larger,
    uint32_t* __restrict__ done_count,
    float* __restrict__ out)
{
    // triangular decode: blockIdx.x -> (bi, bj) with bi <= bj
    int t = blockIdx.x, bi = 0, rem = NT;
    while (t >= rem) { t -= rem; ++bi; --rem; }
    const int bj = bi + t;
    const bool offdiag = (bi != bj);
    const int rowBase = bi * 128;
    const int colBase = bj * 128;

    const int tid  = threadIdx.x;
    const int wave = tid >> 6;
    const int lane = tid & 63;
    const int wi   = wave >> 1;       // wave row in 2x2 grid
    const int wj   = wave & 1;        // wave col
    const int quad = lane >> 4;
    const int l15  = lane & 15;

    // Per-lane fragment base pointers: frag(mi, kt) = base + mi*16*DN + kt*32.
    const uint16_t* aBase = Abf + (size_t)(rowBase + wi * 64 + l15) * DN + quad * 8;
    const uint16_t* bBase = Abf + (size_t)(colBase + wj * 64 + l15) * DN + quad * 8;

    float4v acc[4][4];
    #pragma unroll
    for (int i = 0; i < 4; ++i)
        #pragma unroll
        for (int j = 0; j < 4; ++j)
            acc[i][j] = (float4v){0.f, 0.f, 0.f, 0.f};

    short8 fA[2][4], fB[2][4];
    #pragma unroll
    for (int m = 0; m < 4; ++m) {
        fA[0][m] = *(const short8*)(aBase + m * 16 * DN);
        fB[0][m] = *(const short8*)(bBase + m * 16 * DN);
    }

    #pragma unroll
    for (int kt = 0; kt < DN / 32; ++kt) {
        const int cur = kt & 1, nxt = cur ^ 1;   // compile-time after unroll
        if (kt < DN / 32 - 1) {
            #pragma unroll
            for (int m = 0; m < 4; ++m) {
                fA[nxt][m] = *(const short8*)(aBase + m * 16 * DN + (kt + 1) * 32);
                fB[nxt][m] = *(const short8*)(bBase + m * 16 * DN + (kt + 1) * 32);
            }
        }
        #pragma unroll
        for (int mi = 0; mi < 4; ++mi)
            #pragma unroll
            for (int mj = 0; mj < 4; ++mj)
                acc[mi][mj] = __builtin_amdgcn_mfma_f32_16x16x32_bf16(
                    fA[cur][mi], fB[cur][mj], acc[mi][mj], 0, 0, 0);
    }

    // ---- epilogue: squared distances, dual-side masked mins ----
    const float INFF = __uint_as_float(INF_U);
    float4 mj_meta[4];
    #pragma unroll
    for (int mj = 0; mj < 4; ++mj)
        mj_meta[mj] = meta[colBase + wj * 64 + mj * 16 + l15];   // C/D col = lane&15

    float cAll[4], cLarger[4];
    #pragma unroll
    for (int mj = 0; mj < 4; ++mj) { cAll[mj] = INFF; cLarger[mj] = INFF; }

    #pragma unroll
    for (int mi = 0; mi < 4; ++mi) {
        #pragma unroll
        for (int r = 0; r < 4; ++r) {
            int row = rowBase + wi * 64 + mi * 16 + quad * 4 + r;  // C/D row = quad*4+reg
            float4 mim = meta[row];          // {sqn, dap, dap^2, label}
            uint32_t li = __float_as_uint(mim.w);
            float mAll = INFF, mLarger = INFF;
            #pragma unroll
            for (int mj = 0; mj < 4; ++mj) {
                float d2 = mim.x + mj_meta[mj].x - 2.0f * acc[mi][mj][r];
                d2 = d2 > 0.f ? d2 : 0.f;
                if (__float_as_uint(mj_meta[mj].w) != li) {
                    mAll = fminf(mAll, d2);
                    // reference: pd (euclidean) > d_ap (squared)  <=>  d2 > dap^2
                    if (d2 > mim.z) mLarger = fminf(mLarger, d2);
                    if (offdiag) {
                        cAll[mj] = fminf(cAll[mj], d2);
                        if (d2 > mj_meta[mj].z) cLarger[mj] = fminf(cLarger[mj], d2);
                    }
                }
            }
            // min across the 16 lanes of this quad (they share `row`, cover 64 cols)
            #pragma unroll
            for (int off = 1; off < 16; off <<= 1) {
                mAll    = fminf(mAll,    __shfl_xor(mAll, off));
                mLarger = fminf(mLarger, __shfl_xor(mLarger, off));
            }
            if (l15 == 0) {
                atomicMin(&min_all[row],    __float_as_uint(mAll));
                atomicMin(&min_larger[row], __float_as_uint(mLarger));
            }
        }
    }
    if (offdiag) {
        // col j = colBase + wj*64 + mj*16 + l15 is shared by the 4 quads
        #pragma unroll
        for (int mj = 0; mj < 4; ++mj) {
            float a0 = cAll[mj], l0 = cLarger[mj];
            a0 = fminf(a0, __shfl_xor(a0, 16)); l0 = fminf(l0, __shfl_xor(l0, 16));
            a0 = fminf(a0, __shfl_xor(a0, 32)); l0 = fminf(l0, __shfl_xor(l0, 32));
            if (quad == 0) {
                int col = colBase + wj * 64 + mj * 16 + l15;
                atomicMin(&min_all[col],    __float_as_uint(a0));
                atomicMin(&min_larger[col], __float_as_uint(l0));
            }
        }
    }

    // ---- last-block finalize: select, sqrt, hinge, mean ----
    __shared__ bool isLast;
    __syncthreads();                      // all this block's atomics issued
    if (tid == 0) {
        __threadfence();                  // make our mins visible device-wide
        isLast = (atomicAdd(done_count, 1u) == NBLK - 1);
    }
    __syncthreads();
    if (isLast) {
        __threadfence();                  // acquire: see all other blocks' mins
        float s = 0.f;
        for (int i = tid; i < BN; i += 256) {
            uint32_t mlu = __hip_atomic_load(&min_larger[i], __ATOMIC_RELAXED, __HIP_MEMORY_SCOPE_AGENT);
            uint32_t mau = __hip_atomic_load(&min_all[i],    __ATOMIC_RELAXED, __HIP_MEMORY_SCOPE_AGENT);
            float dan2 = (mlu != INF_U) ? __uint_as_float(mlu) : __uint_as_float(mau);
            float l = meta[i].y - sqrtf(dan2) + MARGIN;
            s += l > 0.f ? l : 0.f;
        }
        #pragma unroll
        for (int off = 32; off; off >>= 1) s += __shfl_xor(s, off);
        __shared__ float wsum[4];
        if ((tid & 63) == 0) wsum[tid >> 6] = s;
        __syncthreads();
        if (tid == 0) out[0] = (wsum[0] + wsum[1] + wsum[2] + wsum[3]) * (1.0f / BN);
    }
}

// ---------------------------------------------------------------------------
extern "C" void kernel_launch(void* const* d_in, const int* in_sizes, int n_in,
                              void* d_out, int out_size, void* d_ws, size_t ws_size,
                              hipStream_t stream) {
    const float* anchor   = (const float*)d_in[0];
    const float* positive = (const float*)d_in[1];
    const int*   labels   = (const int*)d_in[2];
    float* out = (float*)d_out;

    // Workspace layout (~4.4 MB)
    uint8_t* ws = (uint8_t*)d_ws;
    uint16_t* Abf        = (uint16_t*)ws;                          // 4 MB bf16 anchor
    float4*   meta       = (float4*)(ws + (size_t)BN * DN * 2);    // 64 KB
    uint32_t* min_all    = (uint32_t*)(meta + BN);                 // 16 KB
    uint32_t* min_larger = min_all + BN;                           // 16 KB
    uint32_t* done_count = min_larger + BN;                        // 4 B

    prep_kernel<<<BN / 4, 256, 0, stream>>>(anchor, positive, labels, Abf, meta,
                                            min_all, min_larger, done_count);
    gram_kernel<<<NBLK, 256, 0, stream>>>(Abf, meta, min_all, min_larger, done_count, out);
}

// Round 6
// 119.949 us; speedup vs baseline: 1.1388x; 1.1388x over previous
//
#include <hip/hip_runtime.h>
#include <hip/hip_bf16.h>
#include <cstdint>
#include <cstddef>

// Problem constants (fixed by the reference: anchor/positive [4096,512] f32, labels [4096] i32)
constexpr int BN = 4096;   // batch
constexpr int DN = 512;    // feature dim
constexpr int NT = BN / 128;              // 32 tiles per dim
constexpr int NBLK = NT * (NT + 1) / 2;   // 528 triangular tile-pairs
constexpr float MARGIN = 0.2f;
constexpr uint32_t INF_U = 0x7f800000u;   // +inf bits; positive-float order == uint order

typedef __attribute__((ext_vector_type(8))) short short8;     // 8 bf16 = 4 VGPRs (MFMA A/B frag)
typedef __attribute__((ext_vector_type(4))) float float4v;    // MFMA C/D frag

// ---------------------------------------------------------------------------
// Kernel 1: per-row stats + bf16 cast of anchor + init of min arrays + counter.
// One wave per row (4 rows / 256-thread block). Lane l owns elems [8l, 8l+8).
// meta[row] = {||a||^2, d_ap(squared), d_ap^2, label-bits}  (one b128 load later)
// ---------------------------------------------------------------------------
__global__ __launch_bounds__(256) void prep_kernel(
    const float* __restrict__ anchor,
    const float* __restrict__ positive,
    const int* __restrict__ labels,
    uint16_t* __restrict__ Abf,        // [BN][DN] bf16 bits
    float4* __restrict__ meta,         // [BN]
    uint32_t* __restrict__ min_all,    // [BN] +inf-initialized (min over d2)
    uint32_t* __restrict__ min_larger, // [BN] +inf-initialized (min over d2)
    uint32_t* __restrict__ done_count) // single counter, zeroed here
{
    const int tid  = threadIdx.x;
    const int wave = tid >> 6;
    const int lane = tid & 63;
    const int row  = blockIdx.x * 4 + wave;

    if (blockIdx.x == 0 && tid == 0) *done_count = 0;

    const float4* arow = (const float4*)(anchor   + (size_t)row * DN);
    const float4* prow = (const float4*)(positive + (size_t)row * DN);

    float4 av0 = arow[lane * 2 + 0], av1 = arow[lane * 2 + 1];
    float4 pv0 = prow[lane * 2 + 0], pv1 = prow[lane * 2 + 1];

    float a[8] = {av0.x, av0.y, av0.z, av0.w, av1.x, av1.y, av1.z, av1.w};
    float p[8] = {pv0.x, pv0.y, pv0.z, pv0.w, pv1.x, pv1.y, pv1.z, pv1.w};

    float s = 0.f, d = 0.f;
    union { uint16_t u[8]; uint4 v; } pk;
    #pragma unroll
    for (int i = 0; i < 8; ++i) {
        s += a[i] * a[i];
        float dx = a[i] - p[i];
        d += dx * dx;
        uint32_t ub = __float_as_uint(a[i]);               // RNE f32 -> bf16
        pk.u[i] = (uint16_t)((ub + 0x7fffu + ((ub >> 16) & 1u)) >> 16);
    }

    ((uint4*)(Abf + (size_t)row * DN))[lane] = pk.v;       // 16B coalesced store

    #pragma unroll
    for (int off = 32; off; off >>= 1) {
        s += __shfl_xor(s, off);
        d += __shfl_xor(d, off);
    }
    if (lane == 0) {
        meta[row] = (float4){s, d, d * d, __uint_as_float((uint32_t)labels[row])};
        min_all[row]    = INF_U;
        min_larger[row] = INF_U;
    }
}

// ---------------------------------------------------------------------------
// Kernel 2: upper-triangular 128x128 tiles of S = A·A^T (bf16 MFMA 16x16x32).
// R4 structure (best measured: LDS staging via plain uint4 loads + ds_write,
// 2 barriers/iter) with BK=128: 4 K-iterations instead of 8 — halves the
// serialized latency chain, doubles per-iter load batch (16 independent b128
// per thread), 256 B staging segments. LDS 2x32 KB -> 2 blocks/CU (matches
// 528/256 = 2.06 anyway). XOR-16 swizzle (slot = chunk ^ row&15): both
// ds_write_b128 and frag ds_read_b128 tile 32 banks evenly (b128 minimum
// 8 phases, 0 extra conflicts). [R5: frag-from-global = 16-segment gathers,
// 71 µs — reverted. R1/R3: global_load_lds chain serialized, 58 µs.]
// Epilogue: squared-distance dual-side masked mins via uint atomicMin.
// Last block (device counter) folds in the finalize: select, sqrt, hinge, mean.
// ---------------------------------------------------------------------------
__global__ __launch_bounds__(256, 2) void gram_kernel(
    const uint16_t* __restrict__ Abf,
    const float4* __restrict__ meta,
    uint32_t* __restrict__ min_all,
    uint32_t* __restrict__ min_larger,
    uint32_t* __restrict__ done_count,
    float* __restrict__ out)
{
    __shared__ uint16_t Abuf[128 * 128];   // 32 KB, row stride 128 elem = 256 B
    __shared__ uint16_t Bbuf[128 * 128];   // 32 KB

    // triangular decode: blockIdx.x -> (bi, bj) with bi <= bj
    int t = blockIdx.x, bi = 0, rem = NT;
    while (t >= rem) { t -= rem; ++bi; --rem; }
    const int bj = bi + t;
    const bool offdiag = (bi != bj);
    const int rowBase = bi * 128;
    const int colBase = bj * 128;

    const int tid  = threadIdx.x;
    const int wave = tid >> 6;
    const int lane = tid & 63;
    const int wi   = wave >> 1;       // wave row in 2x2 grid
    const int wj   = wave & 1;        // wave col
    const int quad = lane >> 4;
    const int l15  = lane & 15;

    // Staging map: tile = 128 rows x 16 chunks of 16B = 2048 chunks; thread
    // handles l = tid + i*256 (i=0..7): row sr=l>>4, global chunk sc=l&15,
    // LDS slot sp = sc ^ (sr&15)  (XOR-16 swizzle).
    int sr[8], sc[8], sp[8];
    #pragma unroll
    for (int i = 0; i < 8; ++i) {
        int l = tid + i * 256;
        sr[i] = l >> 4; sc[i] = l & 15; sp[i] = sc[i] ^ (sr[i] & 15);
    }

    float4v acc[4][4];
    #pragma unroll
    for (int i = 0; i < 4; ++i)
        #pragma unroll
        for (int j = 0; j < 4; ++j)
            acc[i][j] = (float4v){0.f, 0.f, 0.f, 0.f};

    for (int kt = 0; kt < DN / 128; ++kt) {
        const int k0 = kt * 128;
        __syncthreads();              // readers of previous tile done
        {
            uint4 st[8];
            #pragma unroll
            for (int i = 0; i < 8; ++i)     // 8 independent loads -> pipeline
                st[i] = *(const uint4*)(Abf + (size_t)(rowBase + sr[i]) * DN + k0 + sc[i] * 8);
            #pragma unroll
            for (int i = 0; i < 8; ++i)
                *(uint4*)(Abuf + sr[i] * 128 + sp[i] * 8) = st[i];
            #pragma unroll
            for (int i = 0; i < 8; ++i)
                st[i] = *(const uint4*)(Abf + (size_t)(colBase + sr[i]) * DN + k0 + sc[i] * 8);
            #pragma unroll
            for (int i = 0; i < 8; ++i)
                *(uint4*)(Bbuf + sr[i] * 128 + sp[i] * 8) = st[i];
        }
        __syncthreads();              // LDS tiles visible

        #pragma unroll
        for (int kk = 0; kk < 4; ++kk) {
            short8 af[4], bfr[4];
            #pragma unroll
            for (int mi = 0; mi < 4; ++mi) {
                int r = wi * 64 + mi * 16 + l15;         // r & 15 == l15
                int p = (kk * 4 + quad) ^ l15;
                af[mi] = *(const short8*)(Abuf + r * 128 + p * 8);
            }
            #pragma unroll
            for (int mj = 0; mj < 4; ++mj) {
                int r = wj * 64 + mj * 16 + l15;
                int p = (kk * 4 + quad) ^ l15;
                bfr[mj] = *(const short8*)(Bbuf + r * 128 + p * 8);
            }
            #pragma unroll
            for (int mi = 0; mi < 4; ++mi)
                #pragma unroll
                for (int mj = 0; mj < 4; ++mj)
                    acc[mi][mj] = __builtin_amdgcn_mfma_f32_16x16x32_bf16(
                        af[mi], bfr[mj], acc[mi][mj], 0, 0, 0);
        }
    }

    // ---- epilogue: squared distances, dual-side masked mins ----
    const float INFF = __uint_as_float(INF_U);
    float4 mj_meta[4];
    #pragma unroll
    for (int mj = 0; mj < 4; ++mj)
        mj_meta[mj] = meta[colBase + wj * 64 + mj * 16 + l15];   // C/D col = lane&15

    float cAll[4], cLarger[4];
    #pragma unroll
    for (int mj = 0; mj < 4; ++mj) { cAll[mj] = INFF; cLarger[mj] = INFF; }

    #pragma unroll
    for (int mi = 0; mi < 4; ++mi) {
        #pragma unroll
        for (int r = 0; r < 4; ++r) {
            int row = rowBase + wi * 64 + mi * 16 + quad * 4 + r;  // C/D row = quad*4+reg
            float4 mim = meta[row];          // {sqn, dap, dap^2, label}
            uint32_t li = __float_as_uint(mim.w);
            float mAll = INFF, mLarger = INFF;
            #pragma unroll
            for (int mj = 0; mj < 4; ++mj) {
                float d2 = mim.x + mj_meta[mj].x - 2.0f * acc[mi][mj][r];
                d2 = d2 > 0.f ? d2 : 0.f;
                if (__float_as_uint(mj_meta[mj].w) != li) {
                    mAll = fminf(mAll, d2);
                    // reference: pd (euclidean) > d_ap (squared)  <=>  d2 > dap^2
                    if (d2 > mim.z) mLarger = fminf(mLarger, d2);
                    if (offdiag) {
                        cAll[mj] = fminf(cAll[mj], d2);
                        if (d2 > mj_meta[mj].z) cLarger[mj] = fminf(cLarger[mj], d2);
                    }
                }
            }
            // min across the 16 lanes of this quad (they share `row`, cover 64 cols)
            #pragma unroll
            for (int off = 1; off < 16; off <<= 1) {
                mAll    = fminf(mAll,    __shfl_xor(mAll, off));
                mLarger = fminf(mLarger, __shfl_xor(mLarger, off));
            }
            if (l15 == 0) {
                atomicMin(&min_all[row],    __float_as_uint(mAll));
                atomicMin(&min_larger[row], __float_as_uint(mLarger));
            }
        }
    }
    if (offdiag) {
        // col j = colBase + wj*64 + mj*16 + l15 is shared by the 4 quads
        #pragma unroll
        for (int mj = 0; mj < 4; ++mj) {
            float a0 = cAll[mj], l0 = cLarger[mj];
            a0 = fminf(a0, __shfl_xor(a0, 16)); l0 = fminf(l0, __shfl_xor(l0, 16));
            a0 = fminf(a0, __shfl_xor(a0, 32)); l0 = fminf(l0, __shfl_xor(l0, 32));
            if (quad == 0) {
                int col = colBase + wj * 64 + mj * 16 + l15;
                atomicMin(&min_all[col],    __float_as_uint(a0));
                atomicMin(&min_larger[col], __float_as_uint(l0));
            }
        }
    }

    // ---- last-block finalize: select, sqrt, hinge, mean ----
    __shared__ bool isLast;
    __syncthreads();                      // all this block's atomics issued
    if (tid == 0) {
        __threadfence();                  // make our mins visible device-wide
        isLast = (atomicAdd(done_count, 1u) == NBLK - 1);
    }
    __syncthreads();
    if (isLast) {
        __threadfence();                  // acquire: see all other blocks' mins
        float s = 0.f;
        for (int i = tid; i < BN; i += 256) {
            uint32_t mlu = __hip_atomic_load(&min_larger[i], __ATOMIC_RELAXED, __HIP_MEMORY_SCOPE_AGENT);
            uint32_t mau = __hip_atomic_load(&min_all[i],    __ATOMIC_RELAXED, __HIP_MEMORY_SCOPE_AGENT);
            float dan2 = (mlu != INF_U) ? __uint_as_float(mlu) : __uint_as_float(mau);
            float l = meta[i].y - sqrtf(dan2) + MARGIN;
            s += l > 0.f ? l : 0.f;
        }
        #pragma unroll
        for (int off = 32; off; off >>= 1) s += __shfl_xor(s, off);
        __shared__ float wsum[4];
        if ((tid & 63) == 0) wsum[tid >> 6] = s;
        __syncthreads();
        if (tid == 0) out[0] = (wsum[0] + wsum[1] + wsum[2] + wsum[3]) * (1.0f / BN);
    }
}

// ---------------------------------------------------------------------------
extern "C" void kernel_launch(void* const* d_in, const int* in_sizes, int n_in,
                              void* d_out, int out_size, void* d_ws, size_t ws_size,
                              hipStream_t stream) {
    const float* anchor   = (const float*)d_in[0];
    const float* positive = (const float*)d_in[1];
    const int*   labels   = (const int*)d_in[2];
    float* out = (float*)d_out;

    // Workspace layout (~4.4 MB)
    uint8_t* ws = (uint8_t*)d_ws;
    uint16_t* Abf        = (uint16_t*)ws;                          // 4 MB bf16 anchor
    float4*   meta       = (float4*)(ws + (size_t)BN * DN * 2);    // 64 KB
    uint32_t* min_all    = (uint32_t*)(meta + BN);                 // 16 KB
    uint32_t* min_larger = min_all + BN;                           // 16 KB
    uint32_t* done_count = min_larger + BN;                        // 4 B

    prep_kernel<<<BN / 4, 256, 0, stream>>>(anchor, positive, labels, Abf, meta,
                                            min_all, min_larger, done_count);
    gram_kernel<<<NBLK, 256, 0, stream>>>(Abf, meta, min_all, min_larger, done_count, out);
}